// Round 7
// baseline (7675.852 us; speedup 1.0000x reference)
//
#include <hip/hip_runtime.h>

#define N      4096
#define NBLK   256
#define NTHR   1024
#define RPB    16           // rows per block  (N / NBLK)
#define R      4            // rows per wave
#define NCK    4            // j-chunks per row (waves sharing a row-group)
#define CHUNK  (N / NCK)    // 1024 columns per chunk
#define TPL    (CHUNK / 64) // 16 elements per lane per row
#define NIT    300

#define LOG2E 1.4426950408889634f

// Lessons encoded here:
//  r1-2: never write to d_ws (unvalidated size => OOB fault => dead container)
//  r0,4: no cooperative launch under graph capture (hang => dead container)
//  r5:   __threadfence() per barrier = full L2 writeback+invalidate (48MB
//        refetch/dispatch, VALUBusy 33%) — NO fences anywhere.
//  r6:   relaxed agent-scope atomics through IF$ are coherent & cheap
//        (absmax 0.0); central 2-phase barrier costs ~4us x 603 = ~2.5ms.
//  r7:   dataflow sync — potentials carry their own epoch tag (u64 =
//        tag<<32 | float bits), double-buffered by parity. Consumers poll
//        the exact words they need; no grid barrier in the Sinkhorn loop.
struct WS {
  float4 xpack[N];   // x0,x1,x2,|x|^2  (every block writes its own full copy
  float4 ypack[N];   //                  => per-XCD L2 serves all pack reads)
  double accC;       // sum of all pairwise distances (for eps)
  double accE;       // final EMD accumulator
};
__device__ WS g_ws;

// tagged, double-buffered potentials: [parity][row]
__device__ unsigned long long g_fsb[2][N];
__device__ unsigned long long g_gsb[2][N];

// barrier state (only 2 barriers left: eps reduction, final reduction)
__device__ unsigned g_arrive[NBLK];
__device__ unsigned g_release;
__device__ unsigned g_dead;

#define AL(p)   __hip_atomic_load((p),  __ATOMIC_RELAXED, __HIP_MEMORY_SCOPE_AGENT)
#define AS(p,v) __hip_atomic_store((p),(v), __ATOMIC_RELAXED, __HIP_MEMORY_SCOPE_AGENT)
#define SPIN_MAX 1048576u   // bounded spin: broken sync => wrong answer, not hang

__device__ __forceinline__ float ex2f(float v) { return __builtin_amdgcn_exp2f(v); }

__device__ __forceinline__ unsigned long long pkpot(unsigned tag, float v) {
  return ((unsigned long long)tag << 32) | (unsigned long long)__float_as_uint(v);
}

// poll a tagged potential until its epoch matches `tag`
__device__ __forceinline__ float poll_pot(const unsigned long long* p, unsigned tag) {
  unsigned long long u = AL(p);
  unsigned t = 0;
  while ((unsigned)(u >> 32) != tag) {
    if (AL(&g_dead)) break;
    if (++t > SPIN_MAX) { AS(&g_dead, 1u); break; }
    __builtin_amdgcn_s_sleep(1);
    u = AL(p);
  }
  return __uint_as_float((unsigned)u);
}

// central grid barrier — used only twice per call now
__device__ __forceinline__ void gbar(unsigned k) {
  __syncthreads();
  if (threadIdx.x == 0) AS(&g_arrive[blockIdx.x], k);
  if (blockIdx.x == 0) {
    if (threadIdx.x < NBLK) {
      unsigned t = 0;
      while (AL(&g_arrive[threadIdx.x]) < k) {
        if (AL(&g_dead)) break;
        if (++t > SPIN_MAX) { AS(&g_dead, 1u); break; }
        __builtin_amdgcn_s_sleep(1);
      }
    }
    __syncthreads();
    if (threadIdx.x == 0) AS(&g_release, k);
  } else if (threadIdx.x == 0) {
    unsigned t = 0;
    while (AL(&g_release) < k) {
      if (AL(&g_dead)) break;
      if (++t > SPIN_MAX) { AS(&g_dead, 1u); break; }
      __builtin_amdgcn_s_sleep(2);
    }
  }
  __syncthreads();
}

// ---------------------------------------------------------------------------
// One logsumexp half-pass, previous-potential offset (single exp/element):
//   e = potIn[j] + nie2*C_ij + (12 + potOwn_prev[i]);  Sigma = sum 2^e
//   potOut[i] = potOwn_prev[i] - log2(Sigma)
// potIn:  tagged buffer holding epoch `tin` (polled)
// bown:   tagged buffer holding own rows at epoch `town` (polled)
// bout:   tagged buffer written at epoch `tout`
__device__ void lse_pass(const float4* __restrict__ rowPack,
                         const float4* __restrict__ colPack,
                         const unsigned long long* __restrict__ bin, unsigned tin,
                         const unsigned long long* __restrict__ bown, unsigned town,
                         unsigned long long* __restrict__ bout, unsigned tout,
                         int rowBase, float nie2, float* part)
{
  const int tid  = threadIdx.x;
  const int lane = tid & 63;
  const int wid  = tid >> 6;   // 0..15
  const int rg   = wid >> 2;   // row-group 0..3
  const int ck   = wid & 3;    // chunk 0..3
  const int r0   = rowBase + rg * R;
  const int j0   = ck * CHUNK + lane;

  // dataflow: poll the 16 column potentials this wave needs (producers are
  // 16 different blocks; values appear as they finish the previous pass)
  float pj[TPL];
#pragma unroll
  for (int t = 0; t < TPL; ++t) pj[t] = poll_pot(&bin[j0 + t * 64], tin);

  float c0[R], c1[R], c2[R], ca[R], F[R], l[R];
#pragma unroll
  for (int r = 0; r < R; ++r) {
    float4 p = rowPack[r0 + r];          // plain cached (own-XCD L2 copy)
    c0[r] = -2.f * p.x; c1[r] = -2.f * p.y; c2[r] = -2.f * p.z; ca[r] = p.w;
    F[r] = 12.0f + poll_pot(&bown[r0 + r], town);
    l[r] = 0.f;
  }

#pragma unroll           // FULL unroll: pj[] must stay in VGPRs
  for (int t = 0; t < TPL; ++t) {
    float4 q = colPack[j0 + t * 64];     // plain cached
    float  b = q.w;
#pragma unroll
    for (int r = 0; r < R; ++r) {
      float d2 = fmaf(c0[r], q.x, fmaf(c1[r], q.y, fmaf(c2[r], q.z, ca[r] + b)));
      float c  = __builtin_amdgcn_sqrtf(fmaxf(d2, 1e-12f));   // C_ij
      float e  = fmaf(nie2, c, pj[t] + F[r]);                 // base-2 exponent
      l[r] += ex2f(e);
    }
  }

  // wave-level butterfly sum (row offset is uniform -> plain adds)
#pragma unroll
  for (int r = 0; r < R; ++r) {
#pragma unroll
    for (int off = 32; off; off >>= 1) l[r] += __shfl_xor(l[r], off);
  }

  if (lane == 0) {
#pragma unroll
    for (int r = 0; r < R; ++r) part[(rg * R + r) * NCK + ck] = l[r];
  }
  __syncthreads();

  if (tid < RPB) {   // one thread per row: merge partials, publish tagged value
    float S = part[tid * NCK + 0] + part[tid * NCK + 1]
            + part[tid * NCK + 2] + part[tid * NCK + 3];
    int row = rowBase + tid;
    float oldv = poll_pot(&bown[row], town);      // already resident
    AS(&bout[row], pkpot(tout, oldv - __builtin_amdgcn_logf(S)));
  }
  __syncthreads();   // protect `part` before reuse
}

// ---------------------------------------------------------------------------
// Full-pair accumulation. emd==0: accC += sum C_ij (no potentials needed).
// emd==1: accE += sum 2^(fs_i+gs_j+nie2*C_ij)*C_ij, potentials at tag NIT.
__device__ void pair_sum(int rowBase, int emd, float nie2, double* ldsd)
{
  const int tid  = threadIdx.x;
  const int lane = tid & 63;
  const int wid  = tid >> 6;
  const int rg   = wid >> 2;
  const int ck   = wid & 3;
  const int r0   = rowBase + rg * R;
  const int j0   = ck * CHUNK + lane;

  float pj[TPL];
#pragma unroll
  for (int t = 0; t < TPL; ++t)
    pj[t] = emd ? poll_pot(&g_gsb[NIT & 1][j0 + t * 64], NIT) : 0.f;

  float c0[R], c1[R], c2[R], ca[R], fr[R];
  double acc[R];
#pragma unroll
  for (int r = 0; r < R; ++r) {
    float4 p = g_ws.xpack[r0 + r];
    c0[r] = -2.f * p.x; c1[r] = -2.f * p.y; c2[r] = -2.f * p.z; ca[r] = p.w;
    fr[r] = emd ? poll_pot(&g_fsb[NIT & 1][r0 + r], NIT) : 0.f;
    acc[r] = 0.0;
  }

#pragma unroll
  for (int t = 0; t < TPL; ++t) {
    float4 q = g_ws.ypack[j0 + t * 64];
    float  b = q.w;
#pragma unroll
    for (int r = 0; r < R; ++r) {
      float d2 = fmaf(c0[r], q.x, fmaf(c1[r], q.y, fmaf(c2[r], q.z, ca[r] + b)));
      float c = __builtin_amdgcn_sqrtf(fmaxf(d2, 1e-12f));
      float term = emd ? ex2f(fmaf(nie2, c, fr[r] + pj[t])) * c : c;
      acc[r] += (double)term;
    }
  }

  double a = (acc[0] + acc[1]) + (acc[2] + acc[3]);
#pragma unroll
  for (int off = 32; off; off >>= 1) a += __shfl_xor(a, off);
  if (lane == 0) ldsd[wid] = a;
  __syncthreads();
  if (tid == 0) {
    double s = 0.0;
#pragma unroll
    for (int w = 0; w < 16; ++w) s += ldsd[w];
    atomicAdd(emd ? &g_ws.accE : &g_ws.accC, s);   // device-scope
  }
  __syncthreads();
}

// ---------------------------------------------------------------------------
// reset: stamp all tag words invalid (0xFFFFFFFF — never an expected tag;
// also covers first-call .bss zeros, where tag 0 would alias epoch 0),
// clear barrier flags and accumulators. Grid: 64 x 256 = 16384 threads.
__global__ void k_init()
{
  int idx = blockIdx.x * blockDim.x + threadIdx.x;
  const unsigned long long none = 0xFFFFFFFFull << 32;
  if (idx < 8192) g_fsb[idx >> 12][idx & 4095] = none;
  else            g_gsb[(idx - 8192) >> 12][idx & 4095] = none;
  if (idx < NBLK) g_arrive[idx] = 0u;
  if (idx == 0) { g_release = 0u; g_dead = 0u; g_ws.accC = 0.0; g_ws.accE = 0.0; }
}

// ---------------------------------------------------------------------------
extern "C" __global__ void __launch_bounds__(NTHR)
emd_all(const float* __restrict__ x, const float* __restrict__ y,
        float* __restrict__ out)
{
  __shared__ float  part[RPB * NCK];
  __shared__ double ldsd[16];

  const int tid = threadIdx.x;
  const int bid = blockIdx.x;
  const int gt  = bid * NTHR + tid;
  const int rowBase = bid * RPB;

  // every block builds the FULL pack arrays (identical values; benign race;
  // gives each XCD L2 a complete copy — no cross-XCD coherence needed)
  for (int i = tid; i < N; i += NTHR) {
    float a0 = x[i * 3 + 0], a1 = x[i * 3 + 1], a2 = x[i * 3 + 2];
    g_ws.xpack[i] = make_float4(a0, a1, a2, fmaf(a0, a0, fmaf(a1, a1, a2 * a2)));
    float b0 = y[i * 3 + 0], b1 = y[i * 3 + 1], b2 = y[i * 3 + 2];
    g_ws.ypack[i] = make_float4(b0, b1, b2, fmaf(b0, b0, fmaf(b1, b1, b2 * b2)));
  }
  // publish own rows' initial potentials (f=g=0 -> transformed -12, tag 0)
  if (tid < RPB) {
    AS(&g_fsb[0][rowBase + tid], pkpot(0u, -12.0f));
    AS(&g_gsb[0][rowBase + tid], pkpot(0u, -12.0f));
  }
  __syncthreads();

  // eps = 0.02 * mean(C) — needs a real reduction barrier (1 of 2)
  pair_sum(rowBase, 0, 0.f, ldsd);
  gbar(1u);
  const float nie2 = -LOG2E /
      (float)(0.02 * AL(&g_ws.accC) / ((double)N * (double)N));

  // 300 Gauss-Seidel Sinkhorn iterations — NO barriers, pure dataflow.
  // f-pass it: reads gs@it (parity it&1), own fs@it; writes fs@it+1.
  // g-pass it: reads fs@it+1, own gs@it; writes gs@it+1.
  for (int it = 0; it < NIT; ++it) {
    lse_pass(g_ws.xpack, g_ws.ypack,
             g_gsb[it & 1], (unsigned)it,
             g_fsb[it & 1], (unsigned)it,
             g_fsb[(it + 1) & 1], (unsigned)(it + 1),
             rowBase, nie2, part);
    lse_pass(g_ws.ypack, g_ws.xpack,
             g_fsb[(it + 1) & 1], (unsigned)(it + 1),
             g_gsb[it & 1], (unsigned)it,
             g_gsb[(it + 1) & 1], (unsigned)(it + 1),
             rowBase, nie2, part);
  }

  // EMD = sum_ij 2^(fs_i+gs_j+nie2*C_ij) * C_ij — barrier 2 of 2
  pair_sum(rowBase, 1, nie2, ldsd);
  gbar(2u);
  if (gt == 0) out[0] = (float)AL(&g_ws.accE);
}

extern "C" void kernel_launch(void* const* d_in, const int* in_sizes, int n_in,
                              void* d_out, int out_size, void* d_ws, size_t ws_size,
                              hipStream_t stream) {
  const float* x = (const float*)d_in[0];
  const float* y = (const float*)d_in[1];
  float* out = (float*)d_out;
  (void)d_ws; (void)ws_size;

  k_init<<<dim3(64), dim3(256), 0, stream>>>();
  emd_all<<<dim3(NBLK), dim3(NTHR), 0, stream>>>(x, y, out);
}